// Round 3
// baseline (113.132 us; speedup 1.0000x reference)
//
#include <hip/hip_runtime.h>
#include <hip/hip_bf16.h>

#define CIN   128
#define HH    64
#define WW    64
#define COUT  256
#define HO    64
#define WO    64
#define NTAP  9
#define KTOT  (CIN*NTAP)   /* 1152 */
#define BK    32
#define NSTEP (KTOT/BK)    /* 36 */
#define NB    8
#define PXB   32           /* pixels per block */

typedef __attribute__((ext_vector_type(8))) short bf16x8;
typedef __attribute__((ext_vector_type(4))) short bf16x4;
typedef __attribute__((ext_vector_type(4))) float f32x4;

struct __align__(16) TapEntry {
  int   i00, i01, i10, i11;    // BYTE offsets into xt's per-image slice
  float w00, w01, w10, w11;
};

static __device__ __forceinline__ ushort f2bf(float v) {
  unsigned u = __float_as_uint(v);
  unsigned rnd = 0x7fffu + ((u >> 16) & 1u);
  return (ushort)((u + rnd) >> 16);
}
static __device__ __forceinline__ float bf2f(short s) {
  return __uint_as_float(((unsigned)(unsigned short)s) << 16);
}

// ---- prep: fused x NCHW f32 -> xt NHWC bf16  +  weight repack ----
__global__ __launch_bounds__(256) void prep(const float* __restrict__ x,
                                            const float* __restrict__ w,
                                            ushort* __restrict__ xt,
                                            ushort* __restrict__ wb) {
  const int blk = blockIdx.x;
  const int tid = threadIdx.x;
  if (blk < NB * HH) {
    const int b = blk >> 6, y = blk & 63;
    const int px = tid & 63, c8 = tid >> 6;
    const float* src = x + (size_t)b * CIN * HH * WW + y * WW + px;
    ushort* dst = xt + (((size_t)(b * HH + y) * WW) + px) * CIN;
    #pragma unroll
    for (int cc = 0; cc < 4; ++cc) {
      const int c0 = cc * 32 + c8 * 8;
      bf16x8 v;
      #pragma unroll
      for (int j = 0; j < 8; ++j)
        v[j] = (short)f2bf(src[(size_t)(c0 + j) * (HH * WW)]);
      *reinterpret_cast<bf16x8*>(dst + c0) = v;
    }
  } else {
    // wb[s][co][kk], s = tap*4+cb, ci = (s&3)*32 + kk ; 4 elems/thread
    const int g = ((blk - NB * HH) * 256 + tid) * 4;
    const int s = g >> 13, rem = g & 8191;
    const int co = rem >> 5, kk0 = rem & 31;
    const int tap = s >> 2;
    bf16x4 o;
    #pragma unroll
    for (int i = 0; i < 4; ++i) {
      const int ci = ((s & 3) << 5) | (kk0 + i);
      o[i] = (short)f2bf(w[(co * CIN + ci) * NTAP + tap]);
    }
    *reinterpret_cast<bf16x4*>(wb + g) = o;
  }
}

// ---- main: fused gather (NHWC bf16) + implicit GEMM, pipelined ----
__global__ __launch_bounds__(256, 4)
void dcn2(const ushort* __restrict__ xt, const float* __restrict__ off,
          const ushort* __restrict__ wb, float* __restrict__ out)
{
  __shared__ TapEntry taps[NTAP * PXB];                // 9216 B
  __shared__ __align__(16) ushort cols[2][PXB * 40];   // 2 x 2560 B (80B rows)

  const int tid = threadIdx.x;
  // b in low 3 bits: all 128 blocks of one image land on one XCD (L2 locality)
  const int b  = blockIdx.x & 7;
  const int ho = (blockIdx.x >> 3) & 63;
  const int ph = blockIdx.x >> 9;          // pixel half: wo in [ph*32, ph*32+32)

  for (int e = tid; e < NTAP * PXB; e += 256) {
    const int k  = e >> 5;
    const int lw = e & 31;
    const int wo = ph * PXB + lw;
    const float* op = off + (((size_t)(b * 18 + 2 * k) * HO + ho) * WO + wo);
    const float dy = op[0];
    const float dx = op[HO * WO];
    const float py  = (float)(ho - 1 + (k / 3)) + dy;
    const float pxf = (float)(wo - 1 + (k % 3)) + dx;
    const float y0f = floorf(py), x0f = floorf(pxf);
    const float fy = py - y0f, fx = pxf - x0f;
    const int y0 = (int)y0f, x0 = (int)x0f;
    const int y1 = y0 + 1,  x1 = x0 + 1;
    const bool vy0 = (unsigned)y0 < HH, vy1 = (unsigned)y1 < HH;
    const bool vx0 = (unsigned)x0 < WW, vx1 = (unsigned)x1 < WW;
    const int cy0 = min(max(y0, 0), HH - 1), cy1 = min(max(y1, 0), HH - 1);
    const int cx0 = min(max(x0, 0), WW - 1), cx1 = min(max(x1, 0), WW - 1);
    TapEntry t;
    t.i00 = (cy0 * WW + cx0) << 8;  t.i01 = (cy0 * WW + cx1) << 8;  // *CIN*2B
    t.i10 = (cy1 * WW + cx0) << 8;  t.i11 = (cy1 * WW + cx1) << 8;
    const float gy = 1.f - fy, gx = 1.f - fx;
    t.w00 = (vy0 && vx0) ? gy * gx : 0.f;
    t.w01 = (vy0 && vx1) ? gy * fx : 0.f;
    t.w10 = (vy1 && vx0) ? fy * gx : 0.f;
    t.w11 = (vy1 && vx1) ? fy * fx : 0.f;
    taps[e] = t;
  }

  const int px   = tid & 31;   // local pixel this thread gathers for
  const int cg   = tid >> 5;   // 0..7: 4 channels each
  const int lane = tid & 63;
  const int grp  = tid >> 6;   // wave: owns co range grp*64..+63
  const int l15  = lane & 15;
  const int q    = lane >> 4;

  f32x4 acc[4][2];
  #pragma unroll
  for (int m = 0; m < 4; ++m)
    #pragma unroll
    for (int n = 0; n < 2; ++n)
      acc[m][n] = 0.f;

  const char* xb = reinterpret_cast<const char*>(xt) + (size_t)b * (HH * WW * CIN * 2);
  const ushort* wbg = wb + (grp * 64 + l15) * BK + q * 8;

  __syncthreads();   // taps ready

  TapEntry te = taps[px];      // tap 0
  TapEntry teN = te;

  // prologue: gather step 0 (tap0, cb0) into buf0; load A frags for step 0
  {
    const int cboff = cg * 8;
    const bf16x4 c00 = *reinterpret_cast<const bf16x4*>(xb + te.i00 + cboff);
    const bf16x4 c01 = *reinterpret_cast<const bf16x4*>(xb + te.i01 + cboff);
    const bf16x4 c10 = *reinterpret_cast<const bf16x4*>(xb + te.i10 + cboff);
    const bf16x4 c11 = *reinterpret_cast<const bf16x4*>(xb + te.i11 + cboff);
    bf16x4 hv;
    #pragma unroll
    for (int j = 0; j < 4; ++j) {
      const float v = te.w00 * bf2f(c00[j]) + te.w01 * bf2f(c01[j])
                    + te.w10 * bf2f(c10[j]) + te.w11 * bf2f(c11[j]);
      hv[j] = (short)f2bf(v);
    }
    *reinterpret_cast<bf16x4*>(
        reinterpret_cast<char*>(cols[0]) + px * 80 + cg * 8) = hv;
  }
  bf16x8 aA[4], aB[4];
  #pragma unroll
  for (int m = 0; m < 4; ++m)
    aA[m] = *reinterpret_cast<const bf16x8*>(wbg + m * 16 * BK);
  __syncthreads();   // buf0 ready

  #pragma unroll 1
  for (int t = 0; t < NSTEP / 2; ++t) {
    // ===== even step s0 = 2t: compute from buf0 with aA; prefetch s0+1 =====
    {
      const int nxt = 2 * t + 1;                  // odd -> same tap as s0's group
      // prefetch taps entry needed at the NEXT even step (nxt2 = 2t+2)
      if ((2 * t + 2) < NSTEP && (((2 * t + 2) & 3) == 0))
        teN = taps[((2 * t + 2) >> 2) * PXB + px];
      const int cboff = (nxt & 3) * 64 + cg * 8;
      const bf16x4 c00 = *reinterpret_cast<const bf16x4*>(xb + te.i00 + cboff);
      const bf16x4 c01 = *reinterpret_cast<const bf16x4*>(xb + te.i01 + cboff);
      const bf16x4 c10 = *reinterpret_cast<const bf16x4*>(xb + te.i10 + cboff);
      const bf16x4 c11 = *reinterpret_cast<const bf16x4*>(xb + te.i11 + cboff);
      #pragma unroll
      for (int m = 0; m < 4; ++m)
        aB[m] = *reinterpret_cast<const bf16x8*>(
                   wbg + (size_t)nxt * (COUT * BK) + m * 16 * BK);
      bf16x8 bbf[2];
      #pragma unroll
      for (int n = 0; n < 2; ++n)
        bbf[n] = *reinterpret_cast<const bf16x8*>(
            reinterpret_cast<const char*>(cols[0]) + (n * 16 + l15) * 80 + q * 16);
      #pragma unroll
      for (int m = 0; m < 4; ++m)
        #pragma unroll
        for (int n = 0; n < 2; ++n)
          acc[m][n] = __builtin_amdgcn_mfma_f32_16x16x32_bf16(
              aA[m], bbf[n], acc[m][n], 0, 0, 0);
      bf16x4 hv;
      #pragma unroll
      for (int j = 0; j < 4; ++j) {
        const float v = te.w00 * bf2f(c00[j]) + te.w01 * bf2f(c01[j])
                      + te.w10 * bf2f(c10[j]) + te.w11 * bf2f(c11[j]);
        hv[j] = (short)f2bf(v);
      }
      *reinterpret_cast<bf16x4*>(
          reinterpret_cast<char*>(cols[1]) + px * 80 + cg * 8) = hv;
      __syncthreads();
    }
    // ===== odd step s1 = 2t+1: compute from buf1 with aB; prefetch s1+1 =====
    {
      const int nxt = 2 * t + 2;
      const bool live = (nxt < NSTEP);
      if (live && ((nxt & 3) == 0)) te = teN;     // new tap group starts at nxt
      bf16x4 c00, c01, c10, c11;
      if (live) {
        const int cboff = (nxt & 3) * 64 + cg * 8;
        c00 = *reinterpret_cast<const bf16x4*>(xb + te.i00 + cboff);
        c01 = *reinterpret_cast<const bf16x4*>(xb + te.i01 + cboff);
        c10 = *reinterpret_cast<const bf16x4*>(xb + te.i10 + cboff);
        c11 = *reinterpret_cast<const bf16x4*>(xb + te.i11 + cboff);
        #pragma unroll
        for (int m = 0; m < 4; ++m)
          aA[m] = *reinterpret_cast<const bf16x8*>(
                     wbg + (size_t)nxt * (COUT * BK) + m * 16 * BK);
      }
      bf16x8 bbf[2];
      #pragma unroll
      for (int n = 0; n < 2; ++n)
        bbf[n] = *reinterpret_cast<const bf16x8*>(
            reinterpret_cast<const char*>(cols[1]) + (n * 16 + l15) * 80 + q * 16);
      #pragma unroll
      for (int m = 0; m < 4; ++m)
        #pragma unroll
        for (int n = 0; n < 2; ++n)
          acc[m][n] = __builtin_amdgcn_mfma_f32_16x16x32_bf16(
              aB[m], bbf[n], acc[m][n], 0, 0, 0);
      if (live) {
        bf16x4 hv;
        #pragma unroll
        for (int j = 0; j < 4; ++j) {
          const float v = te.w00 * bf2f(c00[j]) + te.w01 * bf2f(c01[j])
                        + te.w10 * bf2f(c10[j]) + te.w11 * bf2f(c11[j]);
          hv[j] = (short)f2bf(v);
        }
        *reinterpret_cast<bf16x4*>(
            reinterpret_cast<char*>(cols[0]) + px * 80 + cg * 8) = hv;
      }
      __syncthreads();
    }
  }

  // ---- epilogue ----
  const int wo0 = ph * PXB;
  #pragma unroll
  for (int m = 0; m < 4; ++m)
    #pragma unroll
    for (int n = 0; n < 2; ++n)
      #pragma unroll
      for (int r = 0; r < 4; ++r) {
        const int co = grp * 64 + m * 16 + q * 4 + r;
        const int wo = wo0 + n * 16 + l15;
        out[(((size_t)b * COUT + co) * HO + ho) * WO + wo] = acc[m][n][r];
      }
}

// ---- fallback (ws too small): round-1 f32-gather path ----
__global__ __launch_bounds__(256, 2)
void dcn_f32(const float* __restrict__ x, const float* __restrict__ off,
             const float* __restrict__ wgt, float* __restrict__ out)
{
  __shared__ TapEntry taps[NTAP * WO];
  __shared__ __align__(16) ushort colsf[WO * 40];
  const int tid = threadIdx.x;
  const int b  = blockIdx.x & 7;
  const int ho = blockIdx.x >> 3;
  for (int e = tid; e < NTAP * WO; e += 256) {
    const int k  = e >> 6;
    const int wo = e & 63;
    const float* op = off + (((size_t)(b * 18 + 2 * k) * HO + ho) * WO + wo);
    const float dy = op[0];
    const float dx = op[HO * WO];
    const float py  = (float)(ho - 1 + (k / 3)) + dy;
    const float pxf = (float)(wo - 1 + (k % 3)) + dx;
    const float y0f = floorf(py), x0f = floorf(pxf);
    const float fy = py - y0f, fx = pxf - x0f;
    const int y0 = (int)y0f, x0 = (int)x0f;
    const int y1 = y0 + 1,  x1 = x0 + 1;
    const bool vy0 = (unsigned)y0 < HH, vy1 = (unsigned)y1 < HH;
    const bool vx0 = (unsigned)x0 < WW, vx1 = (unsigned)x1 < WW;
    const int cy0 = min(max(y0, 0), HH - 1), cy1 = min(max(y1, 0), HH - 1);
    const int cx0 = min(max(x0, 0), WW - 1), cx1 = min(max(x1, 0), WW - 1);
    TapEntry t;
    t.i00 = cy0 * WW + cx0; t.i01 = cy0 * WW + cx1;
    t.i10 = cy1 * WW + cx0; t.i11 = cy1 * WW + cx1;
    const float gy = 1.f - fy, gx = 1.f - fx;
    t.w00 = (vy0 && vx0) ? gy * gx : 0.f;
    t.w01 = (vy0 && vx1) ? gy * fx : 0.f;
    t.w10 = (vy1 && vx0) ? fy * gx : 0.f;
    t.w11 = (vy1 && vx1) ? fy * fx : 0.f;
    taps[e] = t;
  }
  const int px = tid & 63, grp = tid >> 6, lane = tid & 63;
  const int l15 = lane & 15, q = lane >> 4;
  f32x4 acc[4][4];
  #pragma unroll
  for (int m = 0; m < 4; ++m)
    #pragma unroll
    for (int n = 0; n < 4; ++n) acc[m][n] = 0.f;
  const float* xb = x + (size_t)b * CIN * HH * WW;
  __syncthreads();
  for (int tap = 0; tap < NTAP; ++tap) {
    const TapEntry e = taps[tap * WO + px];
    for (int cb = 0; cb < 4; ++cb) {
      __syncthreads();
      {
        const float* xp = xb + (size_t)(cb * 32 + grp * 8) * (HH * WW);
        bf16x8 hv;
        #pragma unroll
        for (int j = 0; j < 8; ++j) {
          const float* p = xp + j * (HH * WW);
          const float v = e.w00 * p[e.i00] + e.w01 * p[e.i01]
                        + e.w10 * p[e.i10] + e.w11 * p[e.i11];
          hv[j] = (short)f2bf(v);
        }
        *reinterpret_cast<bf16x8*>(
            reinterpret_cast<char*>(colsf) + px * 80 + grp * 16) = hv;
      }
      __syncthreads();
      bf16x8 a[4], bbf[4];
      #pragma unroll
      for (int m = 0; m < 4; ++m) {
        const int co = grp * 64 + m * 16 + l15;
        bf16x8 t;
        #pragma unroll
        for (int j = 0; j < 8; ++j)
          t[j] = (short)f2bf(wgt[(size_t)(co * CIN + cb * 32 + q * 8 + j) * NTAP + tap]);
        a[m] = t;
      }
      #pragma unroll
      for (int n = 0; n < 4; ++n)
        bbf[n] = *reinterpret_cast<const bf16x8*>(
            reinterpret_cast<const char*>(colsf) + (n * 16 + l15) * 80 + q * 16);
      #pragma unroll
      for (int m = 0; m < 4; ++m)
        #pragma unroll
        for (int n = 0; n < 4; ++n)
          acc[m][n] = __builtin_amdgcn_mfma_f32_16x16x32_bf16(
              a[m], bbf[n], acc[m][n], 0, 0, 0);
    }
  }
  const int wco = grp * 64;
  #pragma unroll
  for (int m = 0; m < 4; ++m)
    #pragma unroll
    for (int n = 0; n < 4; ++n)
      #pragma unroll
      for (int r = 0; r < 4; ++r) {
        const int co = wco + m * 16 + q * 4 + r;
        const int wo = n * 16 + l15;
        out[(((size_t)b * COUT + co) * HO + ho) * WO + wo] = acc[m][n][r];
      }
}

extern "C" void kernel_launch(void* const* d_in, const int* in_sizes, int n_in,
                              void* d_out, int out_size, void* d_ws, size_t ws_size,
                              hipStream_t stream) {
  const float* x   = (const float*)d_in[0];   // [8,128,64,64]
  const float* off = (const float*)d_in[1];   // [8,18,64,64]
  const float* wgt = (const float*)d_in[2];   // [256,128,3,3]
  float* out = (float*)d_out;                 // [8,256,64,64]

  const size_t xt_bytes = (size_t)NB * HH * WW * CIN * sizeof(ushort);   // 8 MiB
  const size_t wb_bytes = (size_t)NSTEP * COUT * BK * sizeof(ushort);    // 576 KiB
  if (ws_size >= xt_bytes + wb_bytes) {
    ushort* xtp = (ushort*)d_ws;
    ushort* wbp = (ushort*)((char*)d_ws + xt_bytes);
    const int wblocks = (NSTEP * COUT * BK) / 1024;   // 288
    prep<<<NB * HH + wblocks, 256, 0, stream>>>(x, wgt, xtp, wbp);
    dcn2<<<NB * HO * 2, 256, 0, stream>>>(xtp, off, wbp, out);
  } else {
    dcn_f32<<<NB * HO, 256, 0, stream>>>(x, off, wgt, out);
  }
}

// Round 4
// 72.130 us; speedup vs baseline: 1.5685x; 1.5685x over previous
//
#include <hip/hip_runtime.h>
#include <hip/hip_bf16.h>

#define CIN   128
#define HH    64
#define WW    64
#define COUT  256
#define HO    64
#define WO    64
#define NTAP  9
#define KTOT  (CIN*NTAP)   /* 1152 */
#define BK    32
#define NSTEP (KTOT/BK)    /* 36 */
#define NB    8

typedef __attribute__((ext_vector_type(8))) short bf16x8;
typedef __attribute__((ext_vector_type(4))) short bf16x4;
typedef __attribute__((ext_vector_type(4))) float f32x4;

struct __align__(16) TapEntry {
  int   i00, i01, i10, i11;    // BYTE offsets into xt's per-image slice
  float w00, w01, w10, w11;
};

static __device__ __forceinline__ ushort f2bf(float v) {
  unsigned u = __float_as_uint(v);
  unsigned rnd = 0x7fffu + ((u >> 16) & 1u);
  return (ushort)((u + rnd) >> 16);
}
static __device__ __forceinline__ float bf2f(short s) {
  return __uint_as_float(((unsigned)(unsigned short)s) << 16);
}

// ---- prep: fused x NCHW f32 -> xt NHWC bf16  +  weight repack ----
__global__ __launch_bounds__(256) void prep(const float* __restrict__ x,
                                            const float* __restrict__ w,
                                            ushort* __restrict__ xt,
                                            ushort* __restrict__ wb) {
  const int blk = blockIdx.x;
  const int tid = threadIdx.x;
  if (blk < NB * HH) {
    const int b = blk >> 6, y = blk & 63;
    const int px = tid & 63, c8 = tid >> 6;
    const float* src = x + (size_t)b * CIN * HH * WW + y * WW + px;
    ushort* dst = xt + (((size_t)(b * HH + y) * WW) + px) * CIN;
    #pragma unroll
    for (int cc = 0; cc < 4; ++cc) {
      const int c0 = cc * 32 + c8 * 8;
      bf16x8 v;
      #pragma unroll
      for (int j = 0; j < 8; ++j)
        v[j] = (short)f2bf(src[(size_t)(c0 + j) * (HH * WW)]);
      *reinterpret_cast<bf16x8*>(dst + c0) = v;
    }
  } else {
    // wb[s][co][kk], s = tap*4+cb, ci = (s&3)*32 + kk ; 4 elems/thread
    const int g = ((blk - NB * HH) * 256 + tid) * 4;
    const int s = g >> 13, rem = g & 8191;
    const int co = rem >> 5, kk0 = rem & 31;
    const int tap = s >> 2;
    bf16x4 o;
    #pragma unroll
    for (int i = 0; i < 4; ++i) {
      const int ci = ((s & 3) << 5) | (kk0 + i);
      o[i] = (short)f2bf(w[(co * CIN + ci) * NTAP + tap]);
    }
    *reinterpret_cast<bf16x4*>(wb + g) = o;
  }
}

// ---- main: line-cooperative gather -> direct B-frags -> implicit GEMM ----
__global__ __launch_bounds__(256, 2)
void dcn3(const ushort* __restrict__ xt, const float* __restrict__ off,
          const ushort* __restrict__ wb, float* __restrict__ out)
{
  __shared__ TapEntry taps[NTAP * WO];                    // 18432 B
  __shared__ __align__(16) ushort cols[2][4 * 64 * 8];    // 2 x 4096 B B-frag store

  const int tid = threadIdx.x;
  // b in low 3 bits: all 64 blocks of one image land on one XCD (L2 locality)
  const int b  = blockIdx.x & 7;
  const int ho = blockIdx.x >> 3;

  for (int e = tid; e < NTAP * WO; e += 256) {
    const int k  = e >> 6;
    const int wo = e & 63;
    const float* op = off + (((size_t)(b * 18 + 2 * k) * HO + ho) * WO + wo);
    const float dy = op[0];
    const float dx = op[HO * WO];
    const float py  = (float)(ho - 1 + (k / 3)) + dy;
    const float pxf = (float)(wo - 1 + (k % 3)) + dx;
    const float y0f = floorf(py), x0f = floorf(pxf);
    const float fy = py - y0f, fx = pxf - x0f;
    const int y0 = (int)y0f, x0 = (int)x0f;
    const int y1 = y0 + 1,  x1 = x0 + 1;
    const bool vy0 = (unsigned)y0 < HH, vy1 = (unsigned)y1 < HH;
    const bool vx0 = (unsigned)x0 < WW, vx1 = (unsigned)x1 < WW;
    const int cy0 = min(max(y0, 0), HH - 1), cy1 = min(max(y1, 0), HH - 1);
    const int cx0 = min(max(x0, 0), WW - 1), cx1 = min(max(x1, 0), WW - 1);
    TapEntry t;
    t.i00 = (cy0 * WW + cx0) << 8;  t.i01 = (cy0 * WW + cx1) << 8;  // *CIN*2B
    t.i10 = (cy1 * WW + cx0) << 8;  t.i11 = (cy1 * WW + cx1) << 8;
    const float gy = 1.f - fy, gx = 1.f - fx;
    t.w00 = (vy0 && vx0) ? gy * gx : 0.f;
    t.w01 = (vy0 && vx1) ? gy * fx : 0.f;
    t.w10 = (vy1 && vx0) ? fy * gx : 0.f;
    t.w11 = (vy1 && vx1) ? fy * fx : 0.f;
    taps[e] = t;
  }

  const int lane = tid & 63;
  const int grp  = tid >> 6;   // wave id: px-group (producer) AND co-group (consumer)
  const int l15  = lane & 15;
  const int q    = lane >> 4;
  // producer identity: pixel = grp*16 + l15, k-chunk = q (channels q*8..q*8+7 of step)
  const int mypx = grp * 16 + l15;

  f32x4 acc[4][4];
  #pragma unroll
  for (int m = 0; m < 4; ++m)
    #pragma unroll
    for (int n = 0; n < 4; ++n)
      acc[m][n] = 0.f;

  const char* xb = reinterpret_cast<const char*>(xt) + (size_t)b * (HH * WW * CIN * 2);
  const ushort* wbg = wb + (grp * 64 + l15) * BK + q * 8;
  const int qb = q * 16;   // byte offset of my chunk within a 64B cb-block

  __syncthreads();   // taps ready

  // ---- prologue: gather step 0 (tap0, cb0) -> B-frags -> cols[0] ----
  {
    const TapEntry te = taps[mypx];
    const bf16x8 c00 = *reinterpret_cast<const bf16x8*>(xb + te.i00 + qb);
    const bf16x8 c01 = *reinterpret_cast<const bf16x8*>(xb + te.i01 + qb);
    const bf16x8 c10 = *reinterpret_cast<const bf16x8*>(xb + te.i10 + qb);
    const bf16x8 c11 = *reinterpret_cast<const bf16x8*>(xb + te.i11 + qb);
    bf16x8 hv;
    #pragma unroll
    for (int j = 0; j < 8; ++j) {
      const float v = te.w00 * bf2f(c00[j]) + te.w01 * bf2f(c01[j])
                    + te.w10 * bf2f(c10[j]) + te.w11 * bf2f(c11[j]);
      hv[j] = (short)f2bf(v);
    }
    *reinterpret_cast<bf16x8*>(
        reinterpret_cast<char*>(cols[0]) + (grp * 64 + lane) * 16) = hv;
  }
  __syncthreads();   // cols[0] ready

  #pragma unroll 2
  for (int s = 0; s < NSTEP; ++s) {
    const int cur = s & 1;
    const int s2  = s + 1;

    // A-fragments for step s (L2; issued first for latency headroom)
    bf16x8 a[4];
    #pragma unroll
    for (int m = 0; m < 4; ++m)
      a[m] = *reinterpret_cast<const bf16x8*>(
                 wbg + (size_t)s * (COUT * BK) + m * 16 * BK);

    // issue next step's 4 corner loads (results consumed after the MFMAs)
    bf16x8 c00, c01, c10, c11;
    float w00, w01, w10, w11;
    if (s2 < NSTEP) {
      const TapEntry te = taps[(s2 >> 2) * WO + mypx];
      const int cboff = (s2 & 3) * 64 + qb;
      c00 = *reinterpret_cast<const bf16x8*>(xb + te.i00 + cboff);
      c01 = *reinterpret_cast<const bf16x8*>(xb + te.i01 + cboff);
      c10 = *reinterpret_cast<const bf16x8*>(xb + te.i10 + cboff);
      c11 = *reinterpret_cast<const bf16x8*>(xb + te.i11 + cboff);
      w00 = te.w00; w01 = te.w01; w10 = te.w10; w11 = te.w11;
    }

    // B-fragments for step s from LDS
    bf16x8 bb[4];
    #pragma unroll
    for (int n = 0; n < 4; ++n)
      bb[n] = *reinterpret_cast<const bf16x8*>(
          reinterpret_cast<const char*>(cols[cur]) + (n * 64 + lane) * 16);

    #pragma unroll
    for (int m = 0; m < 4; ++m)
      #pragma unroll
      for (int n = 0; n < 4; ++n)
        acc[m][n] = __builtin_amdgcn_mfma_f32_16x16x32_bf16(
            a[m], bb[n], acc[m][n], 0, 0, 0);

    // combine next step's corners -> B-frag -> other buffer
    if (s2 < NSTEP) {
      bf16x8 hv;
      #pragma unroll
      for (int j = 0; j < 8; ++j) {
        const float v = w00 * bf2f(c00[j]) + w01 * bf2f(c01[j])
                      + w10 * bf2f(c10[j]) + w11 * bf2f(c11[j]);
        hv[j] = (short)f2bf(v);
      }
      *reinterpret_cast<bf16x8*>(
          reinterpret_cast<char*>(cols[cur ^ 1]) + (grp * 64 + lane) * 16) = hv;
    }
    __syncthreads();
  }

  // ---- epilogue: D row(co) = q*4+r (+m*16), col(wo) = l15 (+n*16) ----
  #pragma unroll
  for (int m = 0; m < 4; ++m)
    #pragma unroll
    for (int n = 0; n < 4; ++n)
      #pragma unroll
      for (int r = 0; r < 4; ++r) {
        const int co = grp * 64 + m * 16 + q * 4 + r;
        const int wo = n * 16 + l15;
        out[(((size_t)b * COUT + co) * HO + ho) * WO + wo] = acc[m][n][r];
      }
}

// ---- fallback (ws too small): round-1 f32-gather path ----
__global__ __launch_bounds__(256, 2)
void dcn_f32(const float* __restrict__ x, const float* __restrict__ off,
             const float* __restrict__ wgt, float* __restrict__ out)
{
  __shared__ TapEntry taps[NTAP * WO];
  __shared__ __align__(16) ushort colsf[WO * 40];
  const int tid = threadIdx.x;
  const int b  = blockIdx.x & 7;
  const int ho = blockIdx.x >> 3;
  for (int e = tid; e < NTAP * WO; e += 256) {
    const int k  = e >> 6;
    const int wo = e & 63;
    const float* op = off + (((size_t)(b * 18 + 2 * k) * HO + ho) * WO + wo);
    const float dy = op[0];
    const float dx = op[HO * WO];
    const float py  = (float)(ho - 1 + (k / 3)) + dy;
    const float pxf = (float)(wo - 1 + (k % 3)) + dx;
    const float y0f = floorf(py), x0f = floorf(pxf);
    const float fy = py - y0f, fx = pxf - x0f;
    const int y0 = (int)y0f, x0 = (int)x0f;
    const int y1 = y0 + 1,  x1 = x0 + 1;
    const bool vy0 = (unsigned)y0 < HH, vy1 = (unsigned)y1 < HH;
    const bool vx0 = (unsigned)x0 < WW, vx1 = (unsigned)x1 < WW;
    const int cy0 = min(max(y0, 0), HH - 1), cy1 = min(max(y1, 0), HH - 1);
    const int cx0 = min(max(x0, 0), WW - 1), cx1 = min(max(x1, 0), WW - 1);
    TapEntry t;
    t.i00 = cy0 * WW + cx0; t.i01 = cy0 * WW + cx1;
    t.i10 = cy1 * WW + cx0; t.i11 = cy1 * WW + cx1;
    const float gy = 1.f - fy, gx = 1.f - fx;
    t.w00 = (vy0 && vx0) ? gy * gx : 0.f;
    t.w01 = (vy0 && vx1) ? gy * fx : 0.f;
    t.w10 = (vy1 && vx0) ? fy * gx : 0.f;
    t.w11 = (vy1 && vx1) ? fy * fx : 0.f;
    taps[e] = t;
  }
  const int px = tid & 63, grp = tid >> 6, lane = tid & 63;
  const int l15 = lane & 15, q = lane >> 4;
  f32x4 acc[4][4];
  #pragma unroll
  for (int m = 0; m < 4; ++m)
    #pragma unroll
    for (int n = 0; n < 4; ++n) acc[m][n] = 0.f;
  const float* xb = x + (size_t)b * CIN * HH * WW;
  __syncthreads();
  for (int tap = 0; tap < NTAP; ++tap) {
    const TapEntry e = taps[tap * WO + px];
    for (int cb = 0; cb < 4; ++cb) {
      __syncthreads();
      {
        const float* xp = xb + (size_t)(cb * 32 + grp * 8) * (HH * WW);
        bf16x8 hv;
        #pragma unroll
        for (int j = 0; j < 8; ++j) {
          const float* p = xp + j * (HH * WW);
          const float v = e.w00 * p[e.i00] + e.w01 * p[e.i01]
                        + e.w10 * p[e.i10] + e.w11 * p[e.i11];
          hv[j] = (short)f2bf(v);
        }
        *reinterpret_cast<bf16x8*>(
            reinterpret_cast<char*>(colsf) + px * 80 + grp * 16) = hv;
      }
      __syncthreads();
      bf16x8 a[4], bbf[4];
      #pragma unroll
      for (int m = 0; m < 4; ++m) {
        const int co = grp * 64 + m * 16 + l15;
        bf16x8 t;
        #pragma unroll
        for (int j = 0; j < 8; ++j)
          t[j] = (short)f2bf(wgt[(size_t)(co * CIN + cb * 32 + q * 8 + j) * NTAP + tap]);
        a[m] = t;
      }
      #pragma unroll
      for (int n = 0; n < 4; ++n)
        bbf[n] = *reinterpret_cast<const bf16x8*>(
            reinterpret_cast<const char*>(colsf) + (n * 16 + l15) * 80 + q * 16);
      #pragma unroll
      for (int m = 0; m < 4; ++m)
        #pragma unroll
        for (int n = 0; n < 4; ++n)
          acc[m][n] = __builtin_amdgcn_mfma_f32_16x16x32_bf16(
              a[m], bbf[n], acc[m][n], 0, 0, 0);
    }
  }
  const int wco = grp * 64;
  #pragma unroll
  for (int m = 0; m < 4; ++m)
    #pragma unroll
    for (int n = 0; n < 4; ++n)
      #pragma unroll
      for (int r = 0; r < 4; ++r) {
        const int co = wco + m * 16 + q * 4 + r;
        const int wo = n * 16 + l15;
        out[(((size_t)b * COUT + co) * HO + ho) * WO + wo] = acc[m][n][r];
      }
}

extern "C" void kernel_launch(void* const* d_in, const int* in_sizes, int n_in,
                              void* d_out, int out_size, void* d_ws, size_t ws_size,
                              hipStream_t stream) {
  const float* x   = (const float*)d_in[0];   // [8,128,64,64]
  const float* off = (const float*)d_in[1];   // [8,18,64,64]
  const float* wgt = (const float*)d_in[2];   // [256,128,3,3]
  float* out = (float*)d_out;                 // [8,256,64,64]

  const size_t xt_bytes = (size_t)NB * HH * WW * CIN * sizeof(ushort);   // 8 MiB
  const size_t wb_bytes = (size_t)NSTEP * COUT * BK * sizeof(ushort);    // 576 KiB
  if (ws_size >= xt_bytes + wb_bytes) {
    ushort* xtp = (ushort*)d_ws;
    ushort* wbp = (ushort*)((char*)d_ws + xt_bytes);
    const int wblocks = (NSTEP * COUT * BK) / 1024;   // 288
    prep<<<NB * HH + wblocks, 256, 0, stream>>>(x, wgt, xtp, wbp);
    dcn3<<<NB * HO, 256, 0, stream>>>(xtp, off, wbp, out);
  } else {
    dcn_f32<<<NB * HO, 256, 0, stream>>>(x, off, wgt, out);
  }
}